// Round 1
// baseline (30330.594 us; speedup 1.0000x reference)
//
#include <hip/hip_runtime.h>
#include <cstdint>

#define V 32000
#define E 128
#define H 1024
#define GG 4096
#define T 64
#define B 32

using u64 = unsigned long long;

// ---------------- helpers ----------------

__device__ __forceinline__ float sigm(float x) { return 1.f / (1.f + expf(-x)); }

__device__ __forceinline__ float cell_update(float ai, float af, float ag, float ao, float& c) {
  float cg = sigm(af) * c + sigm(ai) * tanhf(ag);
  c = cg;
  return sigm(ao) * tanhf(cg);
}

// 4-gate dot: rows wb, wb+gs, wb+2gs, wb+3gs (gate stride gs), shared x, length K
__device__ __forceinline__ void dot_g(const float* __restrict__ x, const float* __restrict__ wb,
                                      size_t gs, int K, float acc[4]) {
  float4 a0 = {0,0,0,0}, a1 = {0,0,0,0}, a2 = {0,0,0,0}, a3 = {0,0,0,0};
  for (int k = 0; k < K; k += 4) {
    const float4 xv = *(const float4*)(x + k);
    const float4 w0 = *(const float4*)(wb + k);
    const float4 w1 = *(const float4*)(wb + gs + k);
    const float4 w2 = *(const float4*)(wb + 2 * gs + k);
    const float4 w3 = *(const float4*)(wb + 3 * gs + k);
    a0.x += xv.x * w0.x; a0.y += xv.y * w0.y; a0.z += xv.z * w0.z; a0.w += xv.w * w0.w;
    a1.x += xv.x * w1.x; a1.y += xv.y * w1.y; a1.z += xv.z * w1.z; a1.w += xv.w * w1.w;
    a2.x += xv.x * w2.x; a2.y += xv.y * w2.y; a2.z += xv.z * w2.z; a2.w += xv.w * w2.w;
    a3.x += xv.x * w3.x; a3.y += xv.y * w3.y; a3.z += xv.z * w3.z; a3.w += xv.w * w3.w;
  }
  acc[0] += (a0.x + a0.y) + (a0.z + a0.w);
  acc[1] += (a1.x + a1.y) + (a1.z + a1.w);
  acc[2] += (a2.x + a2.y) + (a2.z + a2.w);
  acc[3] += (a3.x + a3.y) + (a3.z + a3.w);
}

__device__ __forceinline__ float dot1(const float* __restrict__ x, const float* __restrict__ w, int K) {
  float4 a = {0,0,0,0};
  for (int k = 0; k < K; k += 4) {
    const float4 xv = *(const float4*)(x + k);
    const float4 wv = *(const float4*)(w + k);
    a.x += xv.x * wv.x; a.y += xv.y * wv.y; a.z += xv.z * wv.z; a.w += xv.w * wv.w;
  }
  return (a.x + a.y) + (a.z + a.w);
}

// ---------------- init kernels ----------------

__global__ void zero_f(float* __restrict__ p, int n) {
  int i = blockIdx.x * 256 + threadIdx.x;
  if (i < n) p[i] = 0.f;
}

__global__ void zero_u64(u64* __restrict__ p, int n) {
  int i = blockIdx.x * 256 + threadIdx.x;
  if (i < n) p[i] = 0ull;
}

// tf_mask may arrive as 1-byte bools (numpy native) or int32; detect deterministically.
__global__ void decode_mask(const unsigned char* __restrict__ raw, int* __restrict__ mask_i) {
  __shared__ int mode; // 1 = u8 layout, 0 = i32 layout
  if (threadIdx.x == 0) {
    int cnt = 0;
    for (int i = 0; i < 64; ++i)
      if ((i & 3) && raw[i]) cnt++;         // i32 layout never has nonzero at i%4!=0
    mode = (cnt > 0) ? 1 : 0;
  }
  __syncthreads();
  int t = threadIdx.x;
  if (t < T) {
    int v;
    if (mode) v = raw[t] ? 1 : 0;
    else      v = ((const int*)raw)[t] ? 1 : 0;
    mask_i[t] = v;
  }
}

// ---------------- encoder: one tick = layer0 step t (blocks 0..127) + layer1 step t-1 (blocks 128..255)
// h histories ping-pong: writer slot = step&1, reader slot = (step-1)&1; slot 1 pre-zeroed for step 0.

__global__ __launch_bounds__(256) void enc_tick(
    int t, const int* __restrict__ src, const float* __restrict__ emb_enc,
    const float* __restrict__ wih0, const float* __restrict__ whh0,
    const float* __restrict__ bih0, const float* __restrict__ bhh0,
    const float* __restrict__ wih1, const float* __restrict__ whh1,
    const float* __restrict__ bih1, const float* __restrict__ bhh1,
    float* __restrict__ ys0, float* __restrict__ h1e,
    float* __restrict__ c0, float* __restrict__ c1)
{
  const int tid = threadIdx.x;
  const int b = tid & 31;
  const int layer = blockIdx.x >> 7;
  const int jj = ((blockIdx.x & 127) << 3) | (tid >> 5);   // 0..1023

  if (layer == 0) {
    if (t >= T) return;
    const float* hprev = ys0 + (size_t)((t + 1) & 1) * (B * H) + b * H;  // (t-1)&1
    const int tok = src[t * B + b];
    const float* x = emb_enc + (size_t)tok * E;
    float acc[4] = { bih0[jj] + bhh0[jj],
                     bih0[jj + H] + bhh0[jj + H],
                     bih0[jj + 2 * H] + bhh0[jj + 2 * H],
                     bih0[jj + 3 * H] + bhh0[jj + 3 * H] };
    dot_g(x, wih0 + (size_t)jj * E, (size_t)H * E, E, acc);
    dot_g(hprev, whh0 + (size_t)jj * H, (size_t)H * H, H, acc);
    float c = c0[b * H + jj];
    float hv = cell_update(acc[0], acc[1], acc[2], acc[3], c);
    c0[b * H + jj] = c;
    ys0[(size_t)(t & 1) * (B * H) + b * H + jj] = hv;
  } else {
    const int s = t - 1;
    if (s < 0) return;
    const float* x = ys0 + (size_t)(s & 1) * (B * H) + b * H;            // L0 output of step s
    const float* hprev = h1e + (size_t)((s + 1) & 1) * (B * H) + b * H;  // (s-1)&1
    float acc[4] = { bih1[jj] + bhh1[jj],
                     bih1[jj + H] + bhh1[jj + H],
                     bih1[jj + 2 * H] + bhh1[jj + 2 * H],
                     bih1[jj + 3 * H] + bhh1[jj + 3 * H] };
    dot_g(x, wih1 + (size_t)jj * H, (size_t)H * H, H, acc);
    dot_g(hprev, whh1 + (size_t)jj * H, (size_t)H * H, H, acc);
    float c = c1[b * H + jj];
    float hv = cell_update(acc[0], acc[1], acc[2], acc[3], c);
    c1[b * H + jj] = c;
    h1e[(size_t)(s & 1) * (B * H) + b * H + jj] = hv;
  }
}

// ---------------- decoder phase A: token select + cell0 (blocks 0..127), h1_prev @ whh1^T partial (blocks 128..639)

__global__ __launch_bounds__(256) void dec_a(
    int t, const int* __restrict__ src, const int* __restrict__ mask_i,
    const u64* __restrict__ packed, const float* __restrict__ emb_dec,
    const float* __restrict__ wih0, const float* __restrict__ whh0,
    const float* __restrict__ bih0, const float* __restrict__ bhh0,
    const float* __restrict__ whh1,
    const float* __restrict__ ys0, const float* __restrict__ h1e,
    float* __restrict__ h0d, const float* __restrict__ h1d,
    float* __restrict__ c0, float* __restrict__ g1p)
{
  const int tid = threadIdx.x;
  if (blockIdx.x < 128) {
    const int b = tid & 31;
    const int jj = ((int)blockIdx.x << 3) | (tid >> 5);
    // token fed into step t = tok[t-1]
    int tok;
    const int tm1 = t - 1;
    if (tm1 == 0) tok = src[b];
    else if (mask_i[tm1]) tok = src[tm1 * B + b];
    else {
      const u64* p = packed + ((size_t)tm1 * B + b) * 8;
      u64 m = p[0];
      #pragma unroll
      for (int g = 1; g < 8; ++g) { u64 x = p[g]; m = m > x ? m : x; }
      tok = (int)(0xFFFFFFFFu - (unsigned)(m & 0xFFFFFFFFull));
    }
    const float* x = emb_dec + (size_t)tok * E;
    const float* hprev = (t == 1) ? (ys0 + (size_t)(B * H))                       // encoder final h0 (slot 1)
                                  : (h0d + (size_t)((t - 1) & 1) * (B * H));
    float acc[4] = { bih0[jj] + bhh0[jj],
                     bih0[jj + H] + bhh0[jj + H],
                     bih0[jj + 2 * H] + bhh0[jj + 2 * H],
                     bih0[jj + 3 * H] + bhh0[jj + 3 * H] };
    dot_g(x, wih0 + (size_t)jj * E, (size_t)H * E, E, acc);
    dot_g(hprev + b * H, whh0 + (size_t)jj * H, (size_t)H * H, H, acc);
    float c = c0[b * H + jj];
    float hv = cell_update(acc[0], acc[1], acc[2], acc[3], c);
    c0[b * H + jj] = c;
    h0d[(size_t)(t & 1) * (B * H) + b * H + jj] = hv;
  } else {
    const int idx = ((int)blockIdx.x - 128) * 256 + tid;
    const int b = idx & 31;
    const int j = idx >> 5;                                  // 0..4095
    const float* hprev = (t == 1) ? (h1e + (size_t)(B * H))  // encoder final h1 (slot 1)
                                  : (h1d + (size_t)((t - 1) & 1) * (B * H));
    g1p[(size_t)b * GG + j] = dot1(hprev + b * H, whh1 + (size_t)j * H, H);
  }
}

// ---------------- decoder phase B: cell1 = gates(h0 @ wih1^T + g1p + biases)

__global__ __launch_bounds__(256) void dec_b(
    int t, const float* __restrict__ wih1,
    const float* __restrict__ bih1, const float* __restrict__ bhh1,
    const float* __restrict__ h0d, float* __restrict__ h1d,
    float* __restrict__ c1, const float* __restrict__ g1p)
{
  const int tid = threadIdx.x;
  const int b = tid & 31;
  const int jj = ((int)blockIdx.x << 3) | (tid >> 5);
  const float* x = h0d + (size_t)(t & 1) * (B * H) + b * H;
  const float* gp = g1p + (size_t)b * GG;
  float acc[4] = { bih1[jj] + bhh1[jj] + gp[jj],
                   bih1[jj + H] + bhh1[jj + H] + gp[jj + H],
                   bih1[jj + 2 * H] + bhh1[jj + 2 * H] + gp[jj + 2 * H],
                   bih1[jj + 3 * H] + bhh1[jj + 3 * H] + gp[jj + 3 * H] };
  dot_g(x, wih1 + (size_t)jj * H, (size_t)H * H, H, acc);
  float c = c1[b * H + jj];
  float hv = cell_update(acc[0], acc[1], acc[2], acc[3], c);
  c1[b * H + jj] = c;
  h1d[(size_t)(t & 1) * (B * H) + b * H + jj] = hv;
}

// ---------------- decoder phase C: FC [B,V] = h1 @ fc_w^T + fc_b, write d_out[t], fused argmax

#define VPT 8   // v per thread
#define VB 64   // v per block (8 lanes * VPT)

__global__ __launch_bounds__(256) void dec_c(
    int t, const float* __restrict__ fc_w, const float* __restrict__ fc_b,
    const float* __restrict__ h1d, float* __restrict__ out,
    u64* __restrict__ packed)
{
  __shared__ float hs[32 * 132];            // h chunk [b][128] padded to 132
  __shared__ u64 red[8][32];
  const int tid = threadIdx.x;
  const int b = tid & 31;
  const int vl = tid >> 5;                  // 0..7
  const int v0 = blockIdx.x * VB;
  const float* h = h1d + (size_t)(t & 1) * (B * H);

  float4 acc[VPT];
  #pragma unroll
  for (int q = 0; q < VPT; ++q) acc[q] = make_float4(0.f, 0.f, 0.f, 0.f);

  for (int kc = 0; kc < H; kc += 128) {
    __syncthreads();
    {
      const int bb = tid >> 3;              // 0..31
      const int kk = (tid & 7) << 4;        // 0..112
      const float* gp = h + (size_t)bb * H + kc + kk;
      float4 x0 = *(const float4*)(gp);
      float4 x1 = *(const float4*)(gp + 4);
      float4 x2 = *(const float4*)(gp + 8);
      float4 x3 = *(const float4*)(gp + 12);
      float* s = hs + bb * 132 + kk;
      *(float4*)(s)      = x0;
      *(float4*)(s + 4)  = x1;
      *(float4*)(s + 8)  = x2;
      *(float4*)(s + 12) = x3;
    }
    __syncthreads();
    const float* hb = hs + b * 132;
    for (int ks = 0; ks < 128; ks += 16) {
      const float4 x0 = *(const float4*)(hb + ks);
      const float4 x1 = *(const float4*)(hb + ks + 4);
      const float4 x2 = *(const float4*)(hb + ks + 8);
      const float4 x3 = *(const float4*)(hb + ks + 12);
      #pragma unroll
      for (int q = 0; q < VPT; ++q) {
        const float* w = fc_w + (size_t)(v0 + (q << 3) + vl) * H + kc + ks;
        const float4 w0 = *(const float4*)(w);
        const float4 w1 = *(const float4*)(w + 4);
        const float4 w2 = *(const float4*)(w + 8);
        const float4 w3 = *(const float4*)(w + 12);
        acc[q].x += x0.x * w0.x; acc[q].y += x0.y * w0.y; acc[q].z += x0.z * w0.z; acc[q].w += x0.w * w0.w;
        acc[q].x += x1.x * w1.x; acc[q].y += x1.y * w1.y; acc[q].z += x1.z * w1.z; acc[q].w += x1.w * w1.w;
        acc[q].x += x2.x * w2.x; acc[q].y += x2.y * w2.y; acc[q].z += x2.z * w2.z; acc[q].w += x2.w * w2.w;
        acc[q].x += x3.x * w3.x; acc[q].y += x3.y * w3.y; acc[q].z += x3.z * w3.z; acc[q].w += x3.w * w3.w;
      }
    }
  }

  u64 best = 0ull;
  #pragma unroll
  for (int q = 0; q < VPT; ++q) {
    const int v = v0 + (q << 3) + vl;
    float val = ((acc[q].x + acc[q].y) + (acc[q].z + acc[q].w)) + fc_b[v];
    out[(size_t)t * (B * V) + (size_t)b * V + v] = val;
    unsigned u = __float_as_uint(val);
    u = (u & 0x80000000u) ? ~u : (u | 0x80000000u);
    u64 pk = ((u64)u << 32) | (u64)(0xFFFFFFFFu - (unsigned)v);   // ties -> smallest v (np.argmax)
    best = best > pk ? best : pk;
  }
  red[vl][b] = best;
  __syncthreads();
  if (tid < 32) {
    u64 m = red[0][tid];
    #pragma unroll
    for (int q = 1; q < 8; ++q) { u64 x = red[q][tid]; m = m > x ? m : x; }
    atomicMax(&packed[((size_t)t * B + tid) * 8 + (blockIdx.x & 7)], m);
  }
}

// ---------------- host ----------------

extern "C" void kernel_launch(void* const* d_in, const int* in_sizes, int n_in,
                              void* d_out, int out_size, void* d_ws, size_t ws_size,
                              hipStream_t stream) {
  const int*   src     = (const int*)d_in[0];
  const void*  tfm     = d_in[1];
  const float* emb_enc = (const float*)d_in[2];
  const float* emb_dec = (const float*)d_in[3];
  const float* fc_w    = (const float*)d_in[4];
  const float* fc_b    = (const float*)d_in[5];
  const float* e_wih0  = (const float*)d_in[6];
  const float* e_whh0  = (const float*)d_in[7];
  const float* e_bih0  = (const float*)d_in[8];
  const float* e_bhh0  = (const float*)d_in[9];
  const float* e_wih1  = (const float*)d_in[10];
  const float* e_whh1  = (const float*)d_in[11];
  const float* e_bih1  = (const float*)d_in[12];
  const float* e_bhh1  = (const float*)d_in[13];
  const float* d_wih0  = (const float*)d_in[14];
  const float* d_whh0  = (const float*)d_in[15];
  const float* d_bih0  = (const float*)d_in[16];
  const float* d_bhh0  = (const float*)d_in[17];
  const float* d_wih1  = (const float*)d_in[18];
  const float* d_whh1  = (const float*)d_in[19];
  const float* d_bih1  = (const float*)d_in[20];
  const float* d_bhh1  = (const float*)d_in[21];

  float* out = (float*)d_out;
  float* wsf = (float*)d_ws;

  // workspace layout (floats): ~1.9 MB total
  float* ys0 = wsf;                 // [2][B][H] enc L0 h ping-pong
  float* h1e = ys0 + 2 * B * H;     // [2][B][H] enc L1 h ping-pong
  float* h0d = h1e + 2 * B * H;     // [2][B][H] dec L0 h ping-pong
  float* h1d = h0d + 2 * B * H;     // [2][B][H] dec L1 h ping-pong
  float* c0  = h1d + 2 * B * H;     // [B][H] (enc then dec, in-place)
  float* c1  = c0 + B * H;
  float* g1p = c1 + B * H;          // [B][4H]
  u64*   packed = (u64*)(g1p + B * GG);      // [T][B][8] argmax atomics
  int*   mask_i = (int*)(packed + T * B * 8);

  // init
  zero_f<<<(B * H + 255) / 256, 256, 0, stream>>>(ys0 + B * H, B * H);   // slot 1 = zeros (step -1)
  zero_f<<<(B * H + 255) / 256, 256, 0, stream>>>(h1e + B * H, B * H);
  zero_f<<<(B * H + 255) / 256, 256, 0, stream>>>(c0, B * H);
  zero_f<<<(B * H + 255) / 256, 256, 0, stream>>>(c1, B * H);
  zero_u64<<<(T * B * 8 + 255) / 256, 256, 0, stream>>>(packed, T * B * 8);
  zero_f<<<(B * V + 255) / 256, 256, 0, stream>>>(out, B * V);           // outputs[0] = 0
  decode_mask<<<1, 64, 0, stream>>>((const unsigned char*)tfm, mask_i);

  // encoder: software-pipelined ticks (L0 step t, L1 step t-1)
  for (int t = 0; t <= T; ++t)
    enc_tick<<<256, 256, 0, stream>>>(t, src, emb_enc,
                                      e_wih0, e_whh0, e_bih0, e_bhh0,
                                      e_wih1, e_whh1, e_bih1, e_bhh1,
                                      ys0, h1e, c0, c1);

  // decoder: steps t = 1..63 (output row t)
  for (int t = 1; t < T; ++t) {
    dec_a<<<640, 256, 0, stream>>>(t, src, mask_i, packed, emb_dec,
                                   d_wih0, d_whh0, d_bih0, d_bhh0, d_whh1,
                                   ys0, h1e, h0d, h1d, c0, g1p);
    dec_b<<<128, 256, 0, stream>>>(t, d_wih1, d_bih1, d_bhh1, h0d, h1d, c1, g1p);
    dec_c<<<500, 256, 0, stream>>>(t, fc_w, fc_b, h1d, out, packed);
  }
}

// Round 2
// 19011.946 us; speedup vs baseline: 1.5953x; 1.5953x over previous
//
#include <hip/hip_runtime.h>
#include <cstdint>

#define V 32000
#define E 128
#define H 1024
#define T 64
#define B 32
#define BH (B * H)

using u64 = unsigned long long;

__device__ __forceinline__ float sigm(float x) { return 1.f / (1.f + expf(-x)); }

// ---------------- LDS layout for cell kernels (floats) ----------------
// zs:   32 rows x ZS_STRIDE  (chunk of x|h for all 32 batch rows)
// part: 2*32*4  (cross-wave K-split partials)
// toks: 32 ints
#define ZS_STRIDE 260   // 260%32==4 -> 4-way LDS read aliasing (acceptable), 16B-aligned rows
#define SMEM_FLOATS (32 * ZS_STRIDE + 256 + 32)

// Accumulate 4 gate partial dots over one staged chunk.
// Thread (b, kq): covers k-range [kq*KC/4, (kq+1)*KC/4) of this chunk.
// WS = full row length of w (K of this phase); wu = w + unit*WS + kc.
template <int KC, int WS>
__device__ __forceinline__ void chunk_accum(const float* __restrict__ zs,
                                            const float* __restrict__ wu,
                                            int b, int kq, float acc[4]) {
  constexpr int KQ = KC / 4;
  const float* zrow = zs + b * ZS_STRIDE + kq * KQ;
  const float* wq = wu + kq * KQ;
  #pragma unroll
  for (int ks = 0; ks < KQ; ks += 16) {
    const float4 z0 = *(const float4*)(zrow + ks);
    const float4 z1 = *(const float4*)(zrow + ks + 4);
    const float4 z2 = *(const float4*)(zrow + ks + 8);
    const float4 z3 = *(const float4*)(zrow + ks + 12);
    #pragma unroll
    for (int g = 0; g < 4; ++g) {
      const float* wp = wq + (size_t)g * (size_t)H * WS + ks;
      const float4 w0 = *(const float4*)(wp);
      const float4 w1 = *(const float4*)(wp + 4);
      const float4 w2 = *(const float4*)(wp + 8);
      const float4 w3 = *(const float4*)(wp + 12);
      acc[g] += z0.x * w0.x + z0.y * w0.y + z0.z * w0.z + z0.w * w0.w
              + z1.x * w1.x + z1.y * w1.y + z1.z * w1.z + z1.w * w1.w
              + z2.x * w2.x + z2.y * w2.y + z2.z * w2.z + z2.w * w2.w
              + z3.x * w3.x + z3.y * w3.y + z3.z * w3.z + z3.w * w3.w;
    }
  }
}

// Generic LSTM cell: gates = x @ wih^T + hprev @ whh^T + bih + bhh, then c/h update.
// Block: 256 threads = 32 b x 4 kq(K-split) x 2 units. 512 blocks per cell.
// MODE 0: x rows = xsrc + b*xstride          (plain)
// MODE 1: x rows = xsrc + tok(b)*E           (decoder token select)
// MODE 2: x rows = xsrc + src[t*B+b]*E       (encoder embedding)
template <int KX, int MODE>
__device__ __forceinline__ void cell_body(
    int bid, int t, const float* __restrict__ xsrc, int xstride,
    const int* __restrict__ src, const int* __restrict__ mask_i,
    const u64* __restrict__ packed,
    const float* __restrict__ wih, const float* __restrict__ whh,
    const float* __restrict__ bih, const float* __restrict__ bhh,
    const float* __restrict__ hprev, float* __restrict__ hout,
    float* __restrict__ cio, float* __restrict__ smem) {
  float* zs = smem;
  float* part = smem + 32 * ZS_STRIDE;
  int* toks = (int*)(smem + 32 * ZS_STRIDE + 256);

  const int tid = threadIdx.x;
  const int b = tid & 31;
  const int kq = (tid >> 5) & 3;
  const int u = tid >> 7;
  const int unit = bid * 2 + u;
  const int bb = tid >> 3, lq = tid & 7;

  if (MODE == 1) {
    if (tid < 32) {
      int tok;
      const int tm1 = t - 1;
      if (tm1 == 0) tok = src[tid];
      else if (mask_i[tm1]) tok = src[tm1 * B + tid];
      else {
        const u64* p = packed + ((size_t)tm1 * B + tid) * 8;
        u64 m = p[0];
        #pragma unroll
        for (int g = 1; g < 8; ++g) { u64 x = p[g]; m = m > x ? m : x; }
        tok = (int)(0xFFFFFFFFu - (unsigned)(m & 0xFFFFFFFFull));
      }
      toks[tid] = tok;
    }
    __syncthreads();
  }

  float acc[4] = {0.f, 0.f, 0.f, 0.f};

  // ---- phase X: K = KX ----
  {
    const float* rowb;
    if (MODE == 0)      rowb = xsrc + (size_t)bb * xstride;
    else if (MODE == 1) rowb = xsrc + (size_t)toks[bb] * E;
    else                rowb = xsrc + (size_t)src[t * B + bb] * E;
    constexpr int KC = (KX >= 256) ? 256 : KX;
    #pragma unroll 1
    for (int kc = 0; kc < KX; kc += KC) {
      #pragma unroll
      for (int j = lq; j < KC / 4; j += 8)
        *(float4*)(zs + bb * ZS_STRIDE + 4 * j) = *(const float4*)(rowb + kc + 4 * j);
      __syncthreads();
      chunk_accum<KC, KX>(zs, wih + (size_t)unit * KX + kc, b, kq, acc);
      __syncthreads();
    }
  }
  // ---- phase H: K = H ----
  {
    const float* rowb = hprev + (size_t)bb * H;
    #pragma unroll 1
    for (int kc = 0; kc < H; kc += 256) {
      #pragma unroll
      for (int j = lq; j < 64; j += 8)
        *(float4*)(zs + bb * ZS_STRIDE + 4 * j) = *(const float4*)(rowb + kc + 4 * j);
      __syncthreads();
      chunk_accum<256, H>(zs, whh + (size_t)unit * H + kc, b, kq, acc);
      __syncthreads();
    }
  }

  // ---- reduce the 4-way K split ----
  #pragma unroll
  for (int g = 0; g < 4; ++g) acc[g] += __shfl_xor(acc[g], 32);
  const int khi = (tid >> 6) & 1;
  const bool low = ((tid >> 5) & 1) == 0;
  if (low && khi == 1)
    *(float4*)(part + (u * 32 + b) * 4) = make_float4(acc[0], acc[1], acc[2], acc[3]);
  __syncthreads();
  if (low && khi == 0) {
    const float4 p = *(const float4*)(part + (u * 32 + b) * 4);
    float gi = acc[0] + p.x + bih[unit]         + bhh[unit];
    float gf = acc[1] + p.y + bih[H + unit]     + bhh[H + unit];
    float gg = acc[2] + p.z + bih[2 * H + unit] + bhh[2 * H + unit];
    float go = acc[3] + p.w + bih[3 * H + unit] + bhh[3 * H + unit];
    float c = cio[b * H + unit];
    c = sigm(gf) * c + sigm(gi) * tanhf(gg);
    cio[b * H + unit] = c;
    hout[b * H + unit] = sigm(go) * tanhf(c);
  }
}

// ---------------- init kernels ----------------

__global__ void zero_f(float* __restrict__ p, int n) {
  int i = blockIdx.x * 256 + threadIdx.x;
  if (i < n) p[i] = 0.f;
}

__global__ void zero_u64(u64* __restrict__ p, int n) {
  int i = blockIdx.x * 256 + threadIdx.x;
  if (i < n) p[i] = 0ull;
}

// tf_mask may arrive as 1-byte bools or int32; detect deterministically.
__global__ void decode_mask(const unsigned char* __restrict__ raw, int* __restrict__ mask_i) {
  __shared__ int mode;
  if (threadIdx.x == 0) {
    int cnt = 0;
    for (int i = 0; i < 64; ++i)
      if ((i & 3) && raw[i]) cnt++;
    mode = (cnt > 0) ? 1 : 0;
  }
  __syncthreads();
  int t = threadIdx.x;
  if (t < T) {
    int v;
    if (mode) v = raw[t] ? 1 : 0;
    else      v = ((const int*)raw)[t] ? 1 : 0;
    mask_i[t] = v;
  }
}

// ---------------- encoder tick: blocks 0..511 = L0 step t, 512..1023 = L1 step t-1 ----------------

__global__ __launch_bounds__(256) void enc_tick(
    int t, const int* __restrict__ src, const float* __restrict__ emb_enc,
    const float* __restrict__ wih0, const float* __restrict__ whh0,
    const float* __restrict__ bih0, const float* __restrict__ bhh0,
    const float* __restrict__ wih1, const float* __restrict__ whh1,
    const float* __restrict__ bih1, const float* __restrict__ bhh1,
    float* __restrict__ ys0, float* __restrict__ h1e,
    float* __restrict__ c0, float* __restrict__ c1) {
  __shared__ float smem[SMEM_FLOATS];
  const int blk = blockIdx.x;
  if (blk < 512) {
    if (t >= T) return;
    cell_body<E, 2>(blk, t, emb_enc, 0, src, nullptr, nullptr,
                    wih0, whh0, bih0, bhh0,
                    ys0 + (size_t)((t + 1) & 1) * BH,
                    ys0 + (size_t)(t & 1) * BH, c0, smem);
  } else {
    const int s = t - 1;
    if (s < 0) return;
    cell_body<H, 0>(blk - 512, s, ys0 + (size_t)(s & 1) * BH, H, nullptr, nullptr, nullptr,
                    wih1, whh1, bih1, bhh1,
                    h1e + (size_t)((s + 1) & 1) * BH,
                    h1e + (size_t)(s & 1) * BH, c1, smem);
  }
}

// ---------------- decoder cell0 (token select + layer0) ----------------

__global__ __launch_bounds__(256) void dec_a(
    int t, const int* __restrict__ src, const int* __restrict__ mask_i,
    const u64* __restrict__ packed, const float* __restrict__ emb_dec,
    const float* __restrict__ wih0, const float* __restrict__ whh0,
    const float* __restrict__ bih0, const float* __restrict__ bhh0,
    const float* __restrict__ ys0, float* __restrict__ h0d,
    float* __restrict__ c0) {
  __shared__ float smem[SMEM_FLOATS];
  const float* hprev = (t == 1) ? (ys0 + (size_t)BH)
                                : (h0d + (size_t)((t - 1) & 1) * BH);
  cell_body<E, 1>(blockIdx.x, t, emb_dec, 0, src, mask_i, packed,
                  wih0, whh0, bih0, bhh0,
                  hprev, h0d + (size_t)(t & 1) * BH, c0, smem);
}

// ---------------- decoder cell1 (both K-phases; no g1p needed) ----------------

__global__ __launch_bounds__(256) void dec_b(
    int t, const float* __restrict__ wih1, const float* __restrict__ whh1,
    const float* __restrict__ bih1, const float* __restrict__ bhh1,
    const float* __restrict__ h0d, const float* __restrict__ h1e,
    float* __restrict__ h1d, float* __restrict__ c1) {
  __shared__ float smem[SMEM_FLOATS];
  const float* hprev = (t == 1) ? (h1e + (size_t)BH)
                                : (h1d + (size_t)((t - 1) & 1) * BH);
  cell_body<H, 0>(blockIdx.x, t, h0d + (size_t)(t & 1) * BH, H, nullptr, nullptr, nullptr,
                  wih1, whh1, bih1, bhh1,
                  hprev, h1d + (size_t)(t & 1) * BH, c1, smem);
}

// ---------------- decoder FC + fused argmax ----------------

#define VPT 8
#define VB 64

__global__ __launch_bounds__(256) void dec_c(
    int t, const float* __restrict__ fc_w, const float* __restrict__ fc_b,
    const float* __restrict__ h1d, float* __restrict__ out,
    u64* __restrict__ packed) {
  __shared__ float hs[32 * 132];          // h chunk; reused as out-tile [32][68]
  __shared__ u64 red[8][32];
  const int tid = threadIdx.x;
  const int b = tid & 31;
  const int vl = tid >> 5;                // 0..7
  const int v0 = blockIdx.x * VB;
  const float* h = h1d + (size_t)(t & 1) * BH;

  float4 acc[VPT];
  #pragma unroll
  for (int q = 0; q < VPT; ++q) acc[q] = make_float4(0.f, 0.f, 0.f, 0.f);

  #pragma unroll 1
  for (int kc = 0; kc < H; kc += 128) {
    __syncthreads();
    {
      const int bb = tid >> 3;
      const int kk = (tid & 7) << 4;
      const float* gp = h + (size_t)bb * H + kc + kk;
      float4 x0 = *(const float4*)(gp);
      float4 x1 = *(const float4*)(gp + 4);
      float4 x2 = *(const float4*)(gp + 8);
      float4 x3 = *(const float4*)(gp + 12);
      float* s = hs + bb * 132 + kk;
      *(float4*)(s) = x0; *(float4*)(s + 4) = x1;
      *(float4*)(s + 8) = x2; *(float4*)(s + 12) = x3;
    }
    __syncthreads();
    const float* hb = hs + b * 132;
    #pragma unroll
    for (int ks = 0; ks < 128; ks += 16) {
      const float4 x0 = *(const float4*)(hb + ks);
      const float4 x1 = *(const float4*)(hb + ks + 4);
      const float4 x2 = *(const float4*)(hb + ks + 8);
      const float4 x3 = *(const float4*)(hb + ks + 12);
      #pragma unroll
      for (int q = 0; q < VPT; ++q) {
        const float* w = fc_w + (size_t)(v0 + (q << 3) + vl) * H + kc + ks;
        const float4 w0 = *(const float4*)(w);
        const float4 w1 = *(const float4*)(w + 4);
        const float4 w2 = *(const float4*)(w + 8);
        const float4 w3 = *(const float4*)(w + 12);
        acc[q].x += x0.x * w0.x; acc[q].y += x0.y * w0.y; acc[q].z += x0.z * w0.z; acc[q].w += x0.w * w0.w;
        acc[q].x += x1.x * w1.x; acc[q].y += x1.y * w1.y; acc[q].z += x1.z * w1.z; acc[q].w += x1.w * w1.w;
        acc[q].x += x2.x * w2.x; acc[q].y += x2.y * w2.y; acc[q].z += x2.z * w2.z; acc[q].w += x2.w * w2.w;
        acc[q].x += x3.x * w3.x; acc[q].y += x3.y * w3.y; acc[q].z += x3.z * w3.z; acc[q].w += x3.w * w3.w;
      }
    }
  }

  u64 best = 0ull;
  float vals[VPT];
  #pragma unroll
  for (int q = 0; q < VPT; ++q) {
    const int v = v0 + (q << 3) + vl;
    float val = ((acc[q].x + acc[q].y) + (acc[q].z + acc[q].w)) + fc_b[v];
    vals[q] = val;
    unsigned uu = __float_as_uint(val);
    uu = (uu & 0x80000000u) ? ~uu : (uu | 0x80000000u);
    u64 pk = ((u64)uu << 32) | (u64)(0xFFFFFFFFu - (unsigned)v);  // ties -> smallest v
    best = best > pk ? best : pk;
  }
  red[vl][b] = best;
  __syncthreads();                         // red ready; hs free for reuse

  float* tile = hs;                        // [32][68]
  #pragma unroll
  for (int q = 0; q < VPT; ++q) tile[b * 68 + (q << 3) + vl] = vals[q];

  if (tid < 32) {
    u64 m = red[0][tid];
    #pragma unroll
    for (int q = 1; q < 8; ++q) { u64 x = red[q][tid]; m = m > x ? m : x; }
    atomicMax(&packed[((size_t)t * B + tid) * 8 + (blockIdx.x & 7)], m);
  }
  __syncthreads();                         // tile ready
  {
    const int bb = tid >> 3, j = tid & 7;
    const float4 o0 = *(const float4*)(tile + bb * 68 + j * 8);
    const float4 o1 = *(const float4*)(tile + bb * 68 + j * 8 + 4);
    float* op = out + (size_t)t * (B * V) + (size_t)bb * V + v0 + j * 8;
    *(float4*)op = o0;
    *(float4*)(op + 4) = o1;
  }
}

// ---------------- host ----------------

extern "C" void kernel_launch(void* const* d_in, const int* in_sizes, int n_in,
                              void* d_out, int out_size, void* d_ws, size_t ws_size,
                              hipStream_t stream) {
  const int*   src     = (const int*)d_in[0];
  const void*  tfm     = d_in[1];
  const float* emb_enc = (const float*)d_in[2];
  const float* emb_dec = (const float*)d_in[3];
  const float* fc_w    = (const float*)d_in[4];
  const float* fc_b    = (const float*)d_in[5];
  const float* e_wih0  = (const float*)d_in[6];
  const float* e_whh0  = (const float*)d_in[7];
  const float* e_bih0  = (const float*)d_in[8];
  const float* e_bhh0  = (const float*)d_in[9];
  const float* e_wih1  = (const float*)d_in[10];
  const float* e_whh1  = (const float*)d_in[11];
  const float* e_bih1  = (const float*)d_in[12];
  const float* e_bhh1  = (const float*)d_in[13];
  const float* d_wih0  = (const float*)d_in[14];
  const float* d_whh0  = (const float*)d_in[15];
  const float* d_bih0  = (const float*)d_in[16];
  const float* d_bhh0  = (const float*)d_in[17];
  const float* d_wih1  = (const float*)d_in[18];
  const float* d_whh1  = (const float*)d_in[19];
  const float* d_bih1  = (const float*)d_in[20];
  const float* d_bhh1  = (const float*)d_in[21];

  float* out = (float*)d_out;
  float* wsf = (float*)d_ws;

  float* ys0 = wsf;                 // [2][B][H]
  float* h1e = ys0 + 2 * BH;        // [2][B][H]
  float* h0d = h1e + 2 * BH;        // [2][B][H]
  float* h1d = h0d + 2 * BH;        // [2][B][H]
  float* c0  = h1d + 2 * BH;        // [B][H]
  float* c1  = c0 + BH;
  u64*   packed = (u64*)(c1 + BH);  // [T][B][8]
  int*   mask_i = (int*)(packed + (size_t)T * B * 8);

  zero_f<<<(BH + 255) / 256, 256, 0, stream>>>(ys0 + BH, BH);
  zero_f<<<(BH + 255) / 256, 256, 0, stream>>>(h1e + BH, BH);
  zero_f<<<(BH + 255) / 256, 256, 0, stream>>>(c0, BH);
  zero_f<<<(BH + 255) / 256, 256, 0, stream>>>(c1, BH);
  zero_u64<<<(T * B * 8 + 255) / 256, 256, 0, stream>>>(packed, T * B * 8);
  zero_f<<<(B * V + 255) / 256, 256, 0, stream>>>(out, B * V);
  decode_mask<<<1, 64, 0, stream>>>((const unsigned char*)tfm, mask_i);

  for (int t = 0; t <= T; ++t)
    enc_tick<<<1024, 256, 0, stream>>>(t, src, emb_enc,
                                       e_wih0, e_whh0, e_bih0, e_bhh0,
                                       e_wih1, e_whh1, e_bih1, e_bhh1,
                                       ys0, h1e, c0, c1);

  for (int t = 1; t < T; ++t) {
    dec_a<<<512, 256, 0, stream>>>(t, src, mask_i, packed, emb_dec,
                                   d_wih0, d_whh0, d_bih0, d_bhh0,
                                   ys0, h0d, c0);
    dec_b<<<512, 256, 0, stream>>>(t, d_wih1, d_whh1, d_bih1, d_bhh1,
                                   h0d, h1e, h1d, c1);
    dec_c<<<500, 256, 0, stream>>>(t, fc_w, fc_b, h1d, out, packed);
  }
}